// Round 3
// baseline (49.982 us; speedup 1.0000x reference)
//
#include <hip/hip_runtime.h>
#include <hip/hip_bf16.h>

#define EPSV 1e-6f

// Two threads per (n,i) row: lanes (2m,2m+1) share row m; half h handles
// j = 4h..4h+3. 16-lane groups = one sample n. Gathers are pruned to the
// entries actually consumed by the pair terms (~50% of off-diagonals), and
// the final reduction is fused via a last-block-done atomic.
__global__ __launch_bounds__(256) void rank_fused(
    const float* __restrict__ durations,
    const float* __restrict__ survival,
    const float* __restrict__ hazard,
    const float* __restrict__ cuts,
    const int* __restrict__ events,
    const float* __restrict__ weights,
    float* __restrict__ partials,
    unsigned int* __restrict__ counter,
    float* __restrict__ out,
    int NE, int K, float inv_count)
{
    __shared__ float s_cuts[256];     // K == 256 here
    __shared__ float s_S [128][9];    // SatT tile (+1 pad)
    __shared__ float s_SM[128][9];    // SatTMinus tile (+1 pad)
    __shared__ float s_red[256];
    __shared__ bool  s_last;

    const int tid = threadIdx.x;
    for (int k = tid; k < K; k += 256) s_cuts[k] = cuts[k];
    __syncthreads();

    const int g  = blockIdx.x * 256 + tid;
    const int r  = g >> 1;          // global row = n*8 + i
    const int h  = g & 1;           // j-half: 0 -> j=0..3, 1 -> j=4..7
    const int ri = tid >> 1;        // row within block tile (0..127)
    const int i  = ri & 7;          // i within sample
    const bool valid = r < NE;

    const float d_i  = valid ? durations[r] : 0.f;
    const int   ev_i = valid ? events[r]    : 0;

    // t0 = largest k with cuts[k] <= d  (analytic guess + exact fixup)
    const float c0 = s_cuts[0], cK = s_cuts[K - 1];
    int t0 = (int)((d_i - c0) * (float)(K - 1) / (cK - c0));
    t0 = max(0, min(t0, K - 1));
    while (t0 + 1 < K && s_cuts[t0 + 1] <= d_i) ++t0;
    while (t0 > 0 && s_cuts[t0] > d_i) --t0;
    const int t1 = (t0 + 1 < K) ? t0 + 1 : K - 1;
    const float T0_i = s_cuts[t0];
    const float dT_i = s_cuts[t1] - T0_i;
    const float t_eps = (cK - c0) / cK;

    const float* __restrict__ srow = survival + (long long)r * K;

    // ---- gather the whole sample's (d, ev) via shuffles (lanes 2j in 16-grp)
    float dAll[8]; int evAll[8];
    #pragma unroll
    for (int j = 0; j < 8; ++j) {
        dAll[j]  = __shfl(d_i,  2 * j, 16);
        evAll[j] = __shfl(ev_i, 2 * j, 16);
    }
    // diag need for this row i: (I_i & any(d_b > d_i)) | any_a(I_a & d_i > d_a)
    bool anyGreater = false, anyActLower = false;
    #pragma unroll
    for (int b = 0; b < 8; ++b) {
        anyGreater  |= (dAll[b] > d_i);
        anyActLower |= (evAll[b] != 0) && (d_i > dAll[b]);
    }
    const bool needDiag = ((ev_i != 0) && anyGreater) || anyActLower;

    // ---- phase 1: per-column metadata + pruned gathers
    float d_j4[4], T0j[4], dTj[4];
    int t0j[4], evj[4];
    bool need[4];
    #pragma unroll
    for (int q = 0; q < 4; ++q) {
        const int j = 4 * h + q;
        const int src = 2 * j;
        d_j4[q] = dAll[j];
        evj[q]  = evAll[j];
        t0j[q]  = __shfl(t0,   src, 16);
        T0j[q]  = __shfl(T0_i, src, 16);
        dTj[q]  = __shfl(dT_i, src, 16);
        if (j == i)
            need[q] = needDiag;
        else
            need[q] = ((ev_i != 0) && (d_j4[q] > d_i)) ||
                      ((evj[q] != 0) && (d_i > d_j4[q]));
        need[q] = need[q] && valid;
    }
    float S0[4], S1[4];
    #pragma unroll
    for (int q = 0; q < 4; ++q) {
        if (need[q]) {
            const int a = t0j[q];
            const int b = (a + 1 < K) ? a + 1 : K - 1;
            S0[q] = srow[a];
            S1[q] = srow[b];
        } else { S0[q] = 1.f; S1[q] = 1.f; }
    }

    // ---- phase 2: hstar, SatT, SatTMinus (only where needed)
    float sT[4], sTM[4];
    #pragma unroll
    for (int q = 0; q < 4; ++q) {
        float vT = 0.f, vTM = 0.f;
        if (need[q]) {
            float hstar;
            if (dTj[q] > 0.f)
                hstar = (__logf(EPSV + S0[q]) - __logf(EPSV + S1[q])) / dTj[q];
            else
                hstar = hazard[(long long)r * K + t0j[q]];   // dead for this data
            vT  = S0[q] * __expf(-(d_j4[q] - T0j[q]) * hstar);
            const float tm = fmaxf(d_j4[q] - t_eps, 0.f);
            vTM = S0[q] * __expf(-(tm - T0j[q]) * hstar);
        }
        sT[q] = vT; sTM[q] = vTM;
        s_S [ri][4 * h + q] = vT;
        s_SM[ri][4 * h + q] = vTM;
    }
    __syncthreads();

    // ---- phase 3: pair terms
    const float I_i = (float)ev_i;
    const float diagS_i = s_S[ri][i];     // SatT[i][i]
    const int rbase = ri & ~7;
    float acc = 0.f;
    #pragma unroll
    for (int q = 0; q < 4; ++q) {
        if (I_i != 0.f && d_j4[q] > d_i) {          // A1 != 0
            const int rj = rbase + 4 * h + q;
            const float I_j = (float)evj[q];
            const int jj = 4 * h + q;
            const float e1 = __expf(diagS_i - s_S[rj][i]);    // dS1[i][j]
            const float e2 = __expf(sTM[q] - s_SM[rj][jj]);   // dS2[i][j]
            const float e3 = __expf(sT[q]  - s_S [rj][jj]);   // dS3[i][j]
            acc += e1 + I_j * e2 + (1.f - I_j) * e3;
        }
    }

    // ---- deterministic wave reduce -> block partial
    #pragma unroll
    for (int off = 32; off > 0; off >>= 1) acc += __shfl_down(acc, off, 64);
    if ((tid & 63) == 0) s_red[tid >> 6] = acc;
    __syncthreads();
    if (tid == 0) {
        partials[blockIdx.x] =
            (s_red[0] + s_red[1]) + (s_red[2] + s_red[3]);
        __threadfence();
        const unsigned int old = atomicAdd(counter, 1u);
        s_last = (old == gridDim.x - 1);
    }
    __syncthreads();

    // ---- last block: fixed-order deterministic finalize
    if (s_last) {
        __threadfence();
        const volatile float* vp = partials;
        float a = 0.f;
        for (int idx = tid; idx < (int)gridDim.x; idx += 256) a += vp[idx];
        s_red[tid] = a;
        __syncthreads();
        #pragma unroll
        for (int off = 128; off > 0; off >>= 1) {
            if (tid < off) s_red[tid] += s_red[tid + off];
            __syncthreads();
        }
        if (tid == 0) out[0] = s_red[0] * weights[0] * inv_count;
    }
}

extern "C" void kernel_launch(void* const* d_in, const int* in_sizes, int n_in,
                              void* d_out, int out_size, void* d_ws, size_t ws_size,
                              hipStream_t stream) {
    const float* durations = (const float*)d_in[0];
    const float* survival  = (const float*)d_in[1];
    const float* hazard    = (const float*)d_in[2];
    const float* weights   = (const float*)d_in[3];
    const float* cuts      = (const float*)d_in[4];
    const int*   events    = (const int*)d_in[5];

    const int NE = in_sizes[0];              // N * 8 rows
    const int K  = in_sizes[4];              // 256
    const int nthreads = NE * 2;             // 2 threads per row
    const int nb = (nthreads + 255) / 256;   // 1024 blocks

    float* partials = (float*)d_ws;
    unsigned int* counter = (unsigned int*)((char*)d_ws + ((nb * 4 + 255) & ~255));
    float* out = (float*)d_out;

    hipMemsetAsync(counter, 0, sizeof(unsigned int), stream);

    const float inv_count = 1.0f / ((float)NE * 8.0f);   // mean over n*e*e
    rank_fused<<<nb, 256, 0, stream>>>(durations, survival, hazard, cuts,
                                       events, weights, partials, counter,
                                       out, NE, K, inv_count);
}

// Round 4
// 19.801 us; speedup vs baseline: 2.5242x; 2.5242x over previous
//
#include <hip/hip_runtime.h>
#include <hip/hip_bf16.h>

#define EPSV 1e-6f

// Two threads per (n,i) row: lanes (2m,2m+1) share row m; half h handles
// j = 4h..4h+3. 16-lane groups = one sample n. Gathers pruned to entries the
// pair terms actually consume (~50% of off-diagonals). Two-kernel reduce
// (no memset / atomic nodes — a 4B memset node costs ~77us in graph replay).
__global__ __launch_bounds__(256) void rank_partial3(
    const float* __restrict__ durations,
    const float* __restrict__ survival,
    const float* __restrict__ hazard,
    const float* __restrict__ cuts,
    const int* __restrict__ events,
    float* __restrict__ partials,
    int NE, int K)
{
    __shared__ float s_cuts[256];     // K == 256 here
    __shared__ float s_S [128][9];    // SatT tile (+1 pad)
    __shared__ float s_SM[128][9];    // SatTMinus tile (+1 pad)
    __shared__ float s_wsum[4];

    const int tid = threadIdx.x;
    for (int k = tid; k < K; k += 256) s_cuts[k] = cuts[k];
    __syncthreads();

    const int g  = blockIdx.x * 256 + tid;
    const int r  = g >> 1;          // global row = n*8 + i
    const int h  = g & 1;           // j-half: 0 -> j=0..3, 1 -> j=4..7
    const int ri = tid >> 1;        // row within block tile (0..127)
    const int i  = ri & 7;          // i within sample
    const bool valid = r < NE;

    const float d_i  = valid ? durations[r] : 0.f;
    const int   ev_i = valid ? events[r]    : 0;

    // t0 = largest k with cuts[k] <= d  (analytic guess + exact fixup)
    const float c0 = s_cuts[0], cK = s_cuts[K - 1];
    int t0 = (int)((d_i - c0) * (float)(K - 1) / (cK - c0));
    t0 = max(0, min(t0, K - 1));
    while (t0 + 1 < K && s_cuts[t0 + 1] <= d_i) ++t0;
    while (t0 > 0 && s_cuts[t0] > d_i) --t0;
    const int t1 = (t0 + 1 < K) ? t0 + 1 : K - 1;
    const float T0_i = s_cuts[t0];
    const float dT_i = s_cuts[t1] - T0_i;
    const float t_eps = (cK - c0) / cK;

    const float* __restrict__ srow = survival + (long long)r * K;

    // whole-sample (d, ev) via shuffles (row j lives on lane 2j of 16-group)
    float dAll[8]; int evAll[8];
    #pragma unroll
    for (int j = 0; j < 8; ++j) {
        dAll[j]  = __shfl(d_i,  2 * j, 16);
        evAll[j] = __shfl(ev_i, 2 * j, 16);
    }
    bool anyGreater = false, anyActLower = false;
    #pragma unroll
    for (int b = 0; b < 8; ++b) {
        anyGreater  |= (dAll[b] > d_i);
        anyActLower |= (evAll[b] != 0) && (d_i > dAll[b]);
    }
    // SatT[i][i]/SatTM[i][i] consumed iff row i has an active pair either way
    const bool needDiag = ((ev_i != 0) && anyGreater) || anyActLower;

    // phase 1: per-column metadata + need flags, then pruned gathers
    float d_j4[4], T0j[4], dTj[4];
    int t0j[4], evj[4];
    bool need[4];
    #pragma unroll
    for (int q = 0; q < 4; ++q) {
        const int j = 4 * h + q;
        const int src = 2 * j;
        d_j4[q] = dAll[j];
        evj[q]  = evAll[j];
        t0j[q]  = __shfl(t0,   src, 16);
        T0j[q]  = __shfl(T0_i, src, 16);
        dTj[q]  = __shfl(dT_i, src, 16);
        if (j == i)
            need[q] = needDiag;
        else  // SatT[i][j] read when pair (j,i) active; SatT row i col j also
              // feeds dS3/dS2 of pair (i,j)
            need[q] = ((ev_i != 0) && (d_j4[q] > d_i)) ||
                      ((evj[q] != 0) && (d_i > d_j4[q]));
        need[q] = need[q] && valid;
    }
    float S0[4], S1[4];
    #pragma unroll
    for (int q = 0; q < 4; ++q) {
        if (need[q]) {
            const int a = t0j[q];
            const int b = (a + 1 < K) ? a + 1 : K - 1;
            S0[q] = srow[a];
            S1[q] = srow[b];
        } else { S0[q] = 1.f; S1[q] = 1.f; }
    }

    // phase 2: hstar, SatT, SatTMinus (only where needed)
    float sT[4], sTM[4];
    #pragma unroll
    for (int q = 0; q < 4; ++q) {
        float vT = 0.f, vTM = 0.f;
        if (need[q]) {
            float hstar;
            if (dTj[q] > 0.f)
                hstar = (__logf(EPSV + S0[q]) - __logf(EPSV + S1[q])) / dTj[q];
            else
                hstar = hazard[(long long)r * K + t0j[q]];   // dead for this data
            vT  = S0[q] * __expf(-(d_j4[q] - T0j[q]) * hstar);
            const float tm = fmaxf(d_j4[q] - t_eps, 0.f);
            vTM = S0[q] * __expf(-(tm - T0j[q]) * hstar);
        }
        sT[q] = vT; sTM[q] = vTM;
        s_S [ri][4 * h + q] = vT;
        s_SM[ri][4 * h + q] = vTM;
    }
    __syncthreads();

    // phase 3: pair terms
    const float I_i = (float)ev_i;
    const float diagS_i = s_S[ri][i];     // SatT[i][i]
    const int rbase = ri & ~7;
    float acc = 0.f;
    #pragma unroll
    for (int q = 0; q < 4; ++q) {
        if (I_i != 0.f && d_j4[q] > d_i) {          // A1 != 0
            const int rj = rbase + 4 * h + q;
            const int jj = 4 * h + q;
            const float I_j = (float)evj[q];
            const float e1 = __expf(diagS_i - s_S[rj][i]);    // dS1[i][j]
            const float e2 = __expf(sTM[q] - s_SM[rj][jj]);   // dS2[i][j]
            const float e3 = __expf(sT[q]  - s_S [rj][jj]);   // dS3[i][j]
            acc += e1 + I_j * e2 + (1.f - I_j) * e3;
        }
    }

    // deterministic wave reduce -> block partial
    #pragma unroll
    for (int off = 32; off > 0; off >>= 1) acc += __shfl_down(acc, off, 64);
    if ((tid & 63) == 0) s_wsum[tid >> 6] = acc;
    __syncthreads();
    if (tid == 0)
        partials[blockIdx.x] = (s_wsum[0] + s_wsum[1]) + (s_wsum[2] + s_wsum[3]);
}

__global__ __launch_bounds__(256) void rank_finalize(
    const float* __restrict__ partials, int nb,
    const float* __restrict__ weights,
    float* __restrict__ out, float inv_count)
{
    __shared__ float s[256];
    const int tid = threadIdx.x;
    float a = 0.f;
    for (int idx = tid; idx < nb; idx += 256) a += partials[idx];
    s[tid] = a;
    __syncthreads();
    #pragma unroll
    for (int off = 128; off > 0; off >>= 1) {
        if (tid < off) s[tid] += s[tid + off];
        __syncthreads();
    }
    if (tid == 0) out[0] = s[0] * weights[0] * inv_count;
}

extern "C" void kernel_launch(void* const* d_in, const int* in_sizes, int n_in,
                              void* d_out, int out_size, void* d_ws, size_t ws_size,
                              hipStream_t stream) {
    const float* durations = (const float*)d_in[0];
    const float* survival  = (const float*)d_in[1];
    const float* hazard    = (const float*)d_in[2];
    const float* weights   = (const float*)d_in[3];
    const float* cuts      = (const float*)d_in[4];
    const int*   events    = (const int*)d_in[5];

    const int NE = in_sizes[0];              // N * 8 rows
    const int K  = in_sizes[4];              // 256
    const int nthreads = NE * 2;             // 2 threads per row
    const int nb = (nthreads + 255) / 256;   // 1024 blocks

    float* partials = (float*)d_ws;
    float* out = (float*)d_out;

    rank_partial3<<<nb, 256, 0, stream>>>(durations, survival, hazard, cuts,
                                          events, partials, NE, K);

    const float inv_count = 1.0f / ((float)NE * 8.0f);   // mean over n*e*e
    rank_finalize<<<1, 256, 0, stream>>>(partials, nb, weights, out, inv_count);
}